// Round 1
// baseline (126.067 us; speedup 1.0000x reference)
//
#include <hip/hip_runtime.h>
#include <math.h>

#define NQ      4
#define QDEPTH  6
#define TPB     256    // 4 waves/block, 1 sample/thread
#define ROWLEN  64

// ---- fast math helpers ----
__device__ __forceinline__ float fast_tanh(float x) {
    // tanh(x) = 1 - 2/(exp(2x)+1); exact at +-inf saturation
    float e = __expf(2.0f * x);
    float r = __builtin_amdgcn_rcpf(e + 1.0f);
    return fmaf(-2.0f, r, 1.0f);
}

// raw barrier that does NOT drain vmcnt (keeps the 16 global loads in
// flight across the per-block precompute); lgkmcnt(0) makes this wave's
// LDS writes visible before other waves cross the barrier.
__device__ __forceinline__ void lds_fence_barrier() {
    asm volatile("s_waitcnt lgkmcnt(0)" ::: "memory");
    __builtin_amdgcn_s_barrier();
}

// ---- 4-qubit real statevector gates (used only in per-block U precompute)
// index i = b0*8 + b1*4 + b2*2 + b3  (wire w <-> bit mask 8>>w)
template<int W>
__device__ __forceinline__ void apply_ry(float st[16], float c, float s) {
    constexpr int M = 8 >> W;
#pragma unroll
    for (int i = 0; i < 16; ++i) {
        if ((i & M) == 0) {
            float a0 = st[i];
            float a1 = st[i | M];
            st[i]     = fmaf(c, a0, -(s * a1));
            st[i | M] = fmaf(s, a0,  (c * a1));
        }
    }
}

template<int C, int T>
__device__ __forceinline__ void apply_cnot(float st[16]) {
    constexpr int MC = 8 >> C;
    constexpr int MT = 8 >> T;
#pragma unroll
    for (int i = 0; i < 16; ++i) {
        if ((i & MC) != 0 && (i & MT) == 0) {
            float tmp = st[i];
            st[i] = st[i | MT];
            st[i | MT] = tmp;
        }
    }
}

__global__ __launch_bounds__(TPB, 4) void dqnet_kernel(
    const float* __restrict__ inp,     // (B, 64)
    const float* __restrict__ pre_w,   // (4, 64)
    const float* __restrict__ pre_b,   // (4,)
    const float* __restrict__ qp,      // (24,)  = (6,4) row-major
    const float* __restrict__ post_w,  // (1, 4)
    const float* __restrict__ post_b,  // (1,)
    float* __restrict__ out)           // (B,)
{
    // Per-wave private 8 KB transpose quadrant (64 rows x 32 cols fp32),
    // XOR-swizzled: float4 (row r, chunk c) lives at slot r*8 + (c ^ (r&7)).
    __shared__ float4 tile[4 * 512];           // 32 KB
    // --- per-block precompute scratch (~4.3 KB extra; 4 blocks/CU still fit) ---
    __shared__ float cs[QDEPTH * NQ], sn[QDEPTH * NQ], gg[16];
    __shared__ float Ush[16][16];   // columns of the fixed 6-layer circuit U
    __shared__ float Msh[16][16];   // M = U^T diag(g) U
    __shared__ float S1[192], S2[144], S3[108];
    __shared__ float Tsh[81];       // 3^4 tensor in per-qubit (1, sin, cos) basis

    const int t = threadIdx.x;
    const int wave = t >> 6;
    const int lane = t & 63;
    const size_t wrow0 = (size_t)blockIdx.x * TPB + wave * 64;  // wave's first row
    const float4* gp = (const float4*)(inp + wrow0 * ROWLEN);   // row r chunk k at gp[r*16+k]
    float4* wt = &tile[wave * 512];
    const float4* pw4 = (const float4*)pre_w;

    // ---- issue ALL 16 global row-loads up front; they stay in flight across
    //      the raw barriers below (only __syncthreads would drain vmcnt) ----
    float4 x0[8], x1[8];
#pragma unroll
    for (int j = 0; j < 8; ++j) {
        int idx = j * 64 + lane;
        int rw = idx >> 3, c = idx & 7;       // row-in-wave, half-row chunk
        x0[j] = gp[rw * 16 + c];
    }
#pragma unroll
    for (int j = 0; j < 8; ++j) {
        int idx = j * 64 + lane;
        int rw = idx >> 3, c = idx & 7;
        x1[j] = gp[rw * 16 + 8 + c];
    }

    // ================= per-block precompute (hidden under HBM latency) =======
    // P0: weight half-angle trig + diagonal observable coeffs g_i
    if (t < QDEPTH * NQ) {
        float h = 0.5f * qp[t];
        cs[t] = __cosf(h);
        sn[t] = __sinf(h);
    } else if (t >= 32 && t < 48) {
        int i = t - 32;
        float v = 0.0f;
#pragma unroll
        for (int w = 0; w < NQ; ++w) {
            float p = post_w[w];
            v += ((i >> (3 - w)) & 1) ? -p : p;
        }
        gg[i] = v;
    }
    lds_fence_barrier();

    // P1: evolve the 16 basis states through the fixed circuit -> U columns
    if (t < 16) {
        float st[16];
#pragma unroll
        for (int i = 0; i < 16; ++i) st[i] = (i == t) ? 1.0f : 0.0f;
#pragma unroll
        for (int k = 0; k < QDEPTH; ++k) {
            apply_cnot<0, 1>(st);
            apply_cnot<2, 3>(st);
            apply_cnot<1, 2>(st);
            apply_ry<0>(st, cs[k * 4 + 0], sn[k * 4 + 0]);
            apply_ry<1>(st, cs[k * 4 + 1], sn[k * 4 + 1]);
            apply_ry<2>(st, cs[k * 4 + 2], sn[k * 4 + 2]);
            apply_ry<3>(st, cs[k * 4 + 3], sn[k * 4 + 3]);
        }
#pragma unroll
        for (int k = 0; k < 16; ++k) Ush[k][t] = st[k];
    }
    lds_fence_barrier();

    // P2: M_ij = sum_k g_k U_ki U_kj  (one entry per thread)
    {
        int i = t >> 4, j = t & 15;
        float m = 0.0f;
#pragma unroll
        for (int k = 0; k < 16; ++k)
            m = fmaf(gg[k] * Ush[k][i], Ush[k][j], m);
        Msh[i][j] = m;
    }
    lds_fence_barrier();

    // Per-qubit ordered-pair products in basis (1, sin, cos):
    //   uu=(1-s)/2  uv=c/2  vu=c/2  vv=(1+s)/2
    // => B rows: const: .5*(p0+p3) ; sin: .5*(p3-p0) ; cos: .5*(p1+p2)
    // P3: contract qubit-0 axis. R[p0][p1][p2][p3] = M[i(p)][j(p)].
    if (t < 192) {
        int e0 = t >> 6, r = t & 63;
        int p1 = r >> 4, p2 = (r >> 2) & 3, p3 = r & 3;
        auto Rv = [&](int p0) {
            int i = ((p0 >> 1) << 3) | ((p1 >> 1) << 2) | ((p2 >> 1) << 1) | (p3 >> 1);
            int j = ((p0 & 1) << 3) | ((p1 & 1) << 2) | ((p2 & 1) << 1) | (p3 & 1);
            return Msh[i][j];
        };
        float v = (e0 == 0) ? 0.5f * (Rv(0) + Rv(3))
                : (e0 == 1) ? 0.5f * (Rv(3) - Rv(0))
                            : 0.5f * (Rv(1) + Rv(2));
        S1[e0 * 64 + r] = v;
    }
    lds_fence_barrier();

    // P4: contract qubit-1 axis
    if (t < 144) {
        int e0 = t / 48, rem = t % 48;
        int e1 = rem >> 4, r2 = rem & 15;
        const float* base = &S1[e0 * 64];
        auto g1 = [&](int p1) { return base[p1 * 16 + r2]; };
        float v = (e1 == 0) ? 0.5f * (g1(0) + g1(3))
                : (e1 == 1) ? 0.5f * (g1(3) - g1(0))
                            : 0.5f * (g1(1) + g1(2));
        S2[(e0 * 3 + e1) * 16 + r2] = v;
    }
    lds_fence_barrier();

    // P5: contract qubit-2 axis
    if (t < 108) {
        int e01 = t / 12, rem = t % 12;
        int e2 = rem >> 2, p3 = rem & 3;
        const float* base = &S2[e01 * 16];
        auto g2 = [&](int p2) { return base[p2 * 4 + p3]; };
        float v = (e2 == 0) ? 0.5f * (g2(0) + g2(3))
                : (e2 == 1) ? 0.5f * (g2(3) - g2(0))
                            : 0.5f * (g2(1) + g2(2));
        S3[(e01 * 3 + e2) * 4 + p3] = v;
    }
    lds_fence_barrier();

    // P6: contract qubit-3 axis -> final 81-coeff tensor (post_b folded into T[0])
    if (t < 81) {
        int e012 = t / 3, e3 = t % 3;
        const float* base = &S3[e012 * 4];
        float v = (e3 == 0) ? 0.5f * (base[0] + base[3])
                : (e3 == 1) ? 0.5f * (base[3] - base[0])
                            : 0.5f * (base[1] + base[2]);
        if (t == 0) v += post_b[0];
        Tsh[t] = v;
    }
    lds_fence_barrier();
    // ================= end precompute =======================================

    // ---- write pass 0 into swizzled LDS (compiler waits vmcnt for x0 only) ----
#pragma unroll
    for (int j = 0; j < 8; ++j) {
        int idx = j * 64 + lane;
        int rw = idx >> 3, c = idx & 7;
        wt[rw * 8 + (c ^ (rw & 7))] = x0[j];
    }

    // ---- pass 0 matvec: my row = lane, cols 0..31 (weights via s_load) ----
    float acc0 = pre_b[0], acc1 = pre_b[1], acc2 = pre_b[2], acc3 = pre_b[3];
#pragma unroll
    for (int i = 0; i < 8; ++i) {
        float4 x  = wt[lane * 8 + (i ^ (lane & 7))];
        float4 w0 = pw4[0 * 16 + i];
        float4 w1 = pw4[1 * 16 + i];
        float4 w2 = pw4[2 * 16 + i];
        float4 w3 = pw4[3 * 16 + i];
        acc0 = fmaf(x.x, w0.x, acc0); acc0 = fmaf(x.y, w0.y, acc0);
        acc0 = fmaf(x.z, w0.z, acc0); acc0 = fmaf(x.w, w0.w, acc0);
        acc1 = fmaf(x.x, w1.x, acc1); acc1 = fmaf(x.y, w1.y, acc1);
        acc1 = fmaf(x.z, w1.z, acc1); acc1 = fmaf(x.w, w1.w, acc1);
        acc2 = fmaf(x.x, w2.x, acc2); acc2 = fmaf(x.y, w2.y, acc2);
        acc2 = fmaf(x.z, w2.z, acc2); acc2 = fmaf(x.w, w2.w, acc2);
        acc3 = fmaf(x.x, w3.x, acc3); acc3 = fmaf(x.y, w3.y, acc3);
        acc3 = fmaf(x.z, w3.z, acc3); acc3 = fmaf(x.w, w3.w, acc3);
    }

    // ---- write + read pass 1 (same slots; in-order DS pipe makes WAR safe) ----
#pragma unroll
    for (int j = 0; j < 8; ++j) {
        int idx = j * 64 + lane;
        int rw = idx >> 3, c = idx & 7;
        wt[rw * 8 + (c ^ (rw & 7))] = x1[j];
    }
#pragma unroll
    for (int i = 0; i < 8; ++i) {
        float4 x  = wt[lane * 8 + (i ^ (lane & 7))];
        float4 w0 = pw4[0 * 16 + 8 + i];
        float4 w1 = pw4[1 * 16 + 8 + i];
        float4 w2 = pw4[2 * 16 + 8 + i];
        float4 w3 = pw4[3 * 16 + 8 + i];
        acc0 = fmaf(x.x, w0.x, acc0); acc0 = fmaf(x.y, w0.y, acc0);
        acc0 = fmaf(x.z, w0.z, acc0); acc0 = fmaf(x.w, w0.w, acc0);
        acc1 = fmaf(x.x, w1.x, acc1); acc1 = fmaf(x.y, w1.y, acc1);
        acc1 = fmaf(x.z, w1.z, acc1); acc1 = fmaf(x.w, w1.w, acc1);
        acc2 = fmaf(x.x, w2.x, acc2); acc2 = fmaf(x.y, w2.y, acc2);
        acc2 = fmaf(x.z, w2.z, acc2); acc2 = fmaf(x.w, w2.w, acc2);
        acc3 = fmaf(x.x, w3.x, acc3); acc3 = fmaf(x.y, w3.y, acc3);
        acc3 = fmaf(x.z, w3.z, acc3); acc3 = fmaf(x.w, w3.w, acc3);
    }

    // ---- full angles: theta = tanh(pre)*pi/2; basis (1, sin, cos) per qubit ----
    const float QH = 1.57079632679489662f;   // pi/2
    float th0 = fast_tanh(acc0) * QH;
    float th1 = fast_tanh(acc1) * QH;
    float th2 = fast_tanh(acc2) * QH;
    float th3 = fast_tanh(acc3) * QH;
    float s0 = __sinf(th0), c0 = __cosf(th0);
    float s1 = __sinf(th1), c1 = __cosf(th1);
    float s2 = __sinf(th2), c2 = __cosf(th2);
    float s3 = __sinf(th3), c3 = __cosf(th3);

    // ---- readout: out = sum_e T[e] * prod_w (1,sin,cos)[e_w]  (~93 FMA) ----
    float r = 0.0f;
#pragma unroll
    for (int e0 = 0; e0 < 3; ++e0) {
        float a0 = 0.0f;
#pragma unroll
        for (int e1 = 0; e1 < 3; ++e1) {
            float a1 = 0.0f;
#pragma unroll
            for (int e2 = 0; e2 < 3; ++e2) {
                const float* tb = &Tsh[((e0 * 3 + e1) * 3 + e2) * 3];
                float w = fmaf(c3, tb[2], fmaf(s3, tb[1], tb[0]));
                a1 = (e2 == 0) ? (a1 + w) : (e2 == 1) ? fmaf(s2, w, a1) : fmaf(c2, w, a1);
            }
            a0 = (e1 == 0) ? (a0 + a1) : (e1 == 1) ? fmaf(s1, a1, a0) : fmaf(c1, a1, a0);
        }
        r = (e0 == 0) ? (r + a0) : (e0 == 1) ? fmaf(s0, a0, r) : fmaf(c0, a0, r);
    }

    out[wrow0 + lane] = r;
}

extern "C" void kernel_launch(void* const* d_in, const int* in_sizes, int n_in,
                              void* d_out, int out_size, void* d_ws, size_t ws_size,
                              hipStream_t stream) {
    const float* inp    = (const float*)d_in[0];
    const float* pre_w  = (const float*)d_in[1];
    const float* pre_b  = (const float*)d_in[2];
    const float* qp     = (const float*)d_in[3];
    const float* post_w = (const float*)d_in[4];
    const float* post_b = (const float*)d_in[5];
    float* out = (float*)d_out;

    int n = in_sizes[0] / ROWLEN;          // batch size (262144)
    int grid = n / TPB;                    // 1024 blocks
    dqnet_kernel<<<grid, TPB, 0, stream>>>(inp, pre_w, pre_b, qp, post_w, post_b, out);
}

// Round 2
// 102.310 us; speedup vs baseline: 1.2322x; 1.2322x over previous
//
#include <hip/hip_runtime.h>
#include <math.h>

#define NQ      4
#define QDEPTH  6
#define TPB     320    // waves 0-3: 64 rows each (256 rows/block); wave 4: precompute
#define ROWLEN  64

// ---- fast math helpers ----
__device__ __forceinline__ float fast_tanh(float x) {
    // tanh(x) = 1 - 2/(exp(2x)+1); exact at +-inf saturation
    float e = __expf(2.0f * x);
    float r = __builtin_amdgcn_rcpf(e + 1.0f);
    return fmaf(-2.0f, r, 1.0f);
}

// intra-wave LDS fence: in-order DS pipe + lgkmcnt(0) + compiler reorder block.
// Only wave 4 uses this (no cross-wave traffic until the final __syncthreads).
__device__ __forceinline__ void wave_lds_fence() {
    asm volatile("s_waitcnt lgkmcnt(0)" ::: "memory");
}

// ---- 4-qubit real statevector gates (used only in wave-4 U precompute)
// index i = b0*8 + b1*4 + b2*2 + b3  (wire w <-> bit mask 8>>w)
template<int W>
__device__ __forceinline__ void apply_ry(float st[16], float c, float s) {
    constexpr int M = 8 >> W;
#pragma unroll
    for (int i = 0; i < 16; ++i) {
        if ((i & M) == 0) {
            float a0 = st[i];
            float a1 = st[i | M];
            st[i]     = fmaf(c, a0, -(s * a1));
            st[i | M] = fmaf(s, a0,  (c * a1));
        }
    }
}

template<int C, int T>
__device__ __forceinline__ void apply_cnot(float st[16]) {
    constexpr int MC = 8 >> C;
    constexpr int MT = 8 >> T;
#pragma unroll
    for (int i = 0; i < 16; ++i) {
        if ((i & MC) != 0 && (i & MT) == 0) {
            float tmp = st[i];
            st[i] = st[i | MT];
            st[i | MT] = tmp;
        }
    }
}

__global__ __launch_bounds__(TPB, 5) void dqnet_kernel(
    const float* __restrict__ inp,     // (B, 64)
    const float* __restrict__ pre_w,   // (4, 64)
    const float* __restrict__ pre_b,   // (4,)
    const float* __restrict__ qp,      // (24,)  = (6,4) row-major
    const float* __restrict__ post_w,  // (1, 4)
    const float* __restrict__ post_b,  // (1,)
    float* __restrict__ out)           // (B,)
{
    // Per-wave private 8 KB transpose quadrant (64 rows x 32 cols fp32),
    // XOR-swizzled: float4 (row r, chunk c) lives at slot r*8 + (c ^ (r&7)).
    __shared__ float4 tile[4 * 512];           // 32 KB (waves 0-3 only)
    // wave-4 precompute scratch (~5.3 KB)
    __shared__ float cs[QDEPTH * NQ], sn[QDEPTH * NQ], gg[16];
    __shared__ float Ush[16][16];   // columns of the fixed 6-layer circuit U
    __shared__ float Msh[16][16];   // M = U^T diag(g) U
    __shared__ float S1[192], S2[144], S3[108];
    __shared__ float4 T4[27];       // final tensor, 4th slot of each triple = pad

    const int t = threadIdx.x;
    const int wave = t >> 6;
    const int lane = t & 63;
    const size_t wrow0 = (size_t)blockIdx.x * 256 + wave * 64;  // waves 0-3 only

    float s0, c0, s1, c1, s2, c2, s3, c3;   // per-sample trig, set by waves 0-3

    if (wave == 4) {
        // ================= dedicated precompute wave =================
        // PA: weight half-angle trig + diagonal observable coeffs g_i
        if (lane < QDEPTH * NQ) {
            float h = 0.5f * qp[lane];
            cs[lane] = __cosf(h);
            sn[lane] = __sinf(h);
        } else if (lane >= 32 && lane < 48) {
            int i = lane - 32;
            float v = 0.0f;
#pragma unroll
            for (int w = 0; w < NQ; ++w) {
                float p = post_w[w];
                v += ((i >> (3 - w)) & 1) ? -p : p;
            }
            gg[i] = v;
        }
        wave_lds_fence();

        // PB: evolve the 16 basis states through the fixed circuit -> U columns
        if (lane < 16) {
            float st[16];
#pragma unroll
            for (int i = 0; i < 16; ++i) st[i] = (i == lane) ? 1.0f : 0.0f;
#pragma unroll
            for (int k = 0; k < QDEPTH; ++k) {
                apply_cnot<0, 1>(st);
                apply_cnot<2, 3>(st);
                apply_cnot<1, 2>(st);
                apply_ry<0>(st, cs[k * 4 + 0], sn[k * 4 + 0]);
                apply_ry<1>(st, cs[k * 4 + 1], sn[k * 4 + 1]);
                apply_ry<2>(st, cs[k * 4 + 2], sn[k * 4 + 2]);
                apply_ry<3>(st, cs[k * 4 + 3], sn[k * 4 + 3]);
            }
#pragma unroll
            for (int k = 0; k < 16; ++k) Ush[k][lane] = st[k];
        }
        wave_lds_fence();

        // PC: M_ij = sum_k g_k U_ki U_kj  (256 entries, 4 per lane)
#pragma unroll
        for (int it = 0; it < 4; ++it) {
            int idx = it * 64 + lane;
            int i = idx >> 4, j = idx & 15;
            float m = 0.0f;
#pragma unroll
            for (int k = 0; k < 16; ++k)
                m = fmaf(gg[k] * Ush[k][i], Ush[k][j], m);
            Msh[i][j] = m;
        }
        wave_lds_fence();

        // Per-qubit ordered-pair products in basis (1, sin, cos):
        //   uu=(1-s)/2  uv=vu=c/2  vv=(1+s)/2
        // => rows: const: .5*(p0+p3) ; sin: .5*(p3-p0) ; cos: .5*(p1+p2)
        // PD: contract qubit-0 axis. R[p0][p1][p2][p3] = M[i(p)][j(p)].
#pragma unroll
        for (int it = 0; it < 3; ++it) {
            int idx = it * 64 + lane;
            int e0 = idx >> 6, r = idx & 63;
            int p1 = r >> 4, p2 = (r >> 2) & 3, p3 = r & 3;
            auto Rv = [&](int p0) {
                int i = ((p0 >> 1) << 3) | ((p1 >> 1) << 2) | ((p2 >> 1) << 1) | (p3 >> 1);
                int j = ((p0 & 1) << 3) | ((p1 & 1) << 2) | ((p2 & 1) << 1) | (p3 & 1);
                return Msh[i][j];
            };
            float v = (e0 == 0) ? 0.5f * (Rv(0) + Rv(3))
                    : (e0 == 1) ? 0.5f * (Rv(3) - Rv(0))
                                : 0.5f * (Rv(1) + Rv(2));
            S1[idx] = v;
        }
        wave_lds_fence();

        // PE: contract qubit-1 axis (144 entries)
#pragma unroll
        for (int it = 0; it < 3; ++it) {
            int idx = it * 64 + lane;
            if (idx < 144) {
                int e0 = idx / 48, rem = idx % 48;
                int e1 = rem >> 4, r2 = rem & 15;
                const float* base = &S1[e0 * 64];
                auto g1 = [&](int p1) { return base[p1 * 16 + r2]; };
                float v = (e1 == 0) ? 0.5f * (g1(0) + g1(3))
                        : (e1 == 1) ? 0.5f * (g1(3) - g1(0))
                                    : 0.5f * (g1(1) + g1(2));
                S2[(e0 * 3 + e1) * 16 + r2] = v;
            }
        }
        wave_lds_fence();

        // PF: contract qubit-2 axis (108 entries)
#pragma unroll
        for (int it = 0; it < 2; ++it) {
            int idx = it * 64 + lane;
            if (idx < 108) {
                int e01 = idx / 12, rem = idx % 12;
                int e2 = rem >> 2, p3 = rem & 3;
                const float* base = &S2[e01 * 16];
                auto g2 = [&](int p2) { return base[p2 * 4 + p3]; };
                float v = (e2 == 0) ? 0.5f * (g2(0) + g2(3))
                        : (e2 == 1) ? 0.5f * (g2(3) - g2(0))
                                    : 0.5f * (g2(1) + g2(2));
                S3[(e01 * 3 + e2) * 4 + p3] = v;
            }
        }
        wave_lds_fence();

        // PG: contract qubit-3 axis -> padded float4 tensor (post_b in T4[0].x)
#pragma unroll
        for (int it = 0; it < 2; ++it) {
            int idx = it * 64 + lane;          // slot = e012*4 + e3, e3==3 is pad
            if (idx < 108) {
                int e3 = idx & 3, e012 = idx >> 2;
                float v = 0.0f;
                if (e3 < 3) {
                    const float* base = &S3[e012 * 4];
                    v = (e3 == 0) ? 0.5f * (base[0] + base[3])
                      : (e3 == 1) ? 0.5f * (base[3] - base[0])
                                  : 0.5f * (base[1] + base[2]);
                    if (idx == 0) v += post_b[0];
                }
                ((float*)T4)[idx] = v;
            }
        }
        // __syncthreads below drains lgkm and publishes T4 to all waves
    } else {
        // ================= matvec waves (round-0 structure, no spills) =======
        const float4* gp = (const float4*)(inp + wrow0 * ROWLEN);
        float4* wt = &tile[wave * 512];
        const float4* pw4 = (const float4*)pre_w;

        // pass 0 loads (cols 0..31), fully coalesced: 8 x 1KB/wave
        float4 x0[8];
#pragma unroll
        for (int j = 0; j < 8; ++j) {
            int idx = j * 64 + lane;
            int rw = idx >> 3, c = idx & 7;       // row-in-wave, half-row chunk
            x0[j] = gp[rw * 16 + c];
        }
        // write pass 0 into swizzled LDS
#pragma unroll
        for (int j = 0; j < 8; ++j) {
            int idx = j * 64 + lane;
            int rw = idx >> 3, c = idx & 7;
            wt[rw * 8 + (c ^ (rw & 7))] = x0[j];
        }
        // issue pass 1 loads (cols 32..63) so HBM latency overlaps pass-0 math
        float4 x1[8];
#pragma unroll
        for (int j = 0; j < 8; ++j) {
            int idx = j * 64 + lane;
            int rw = idx >> 3, c = idx & 7;
            x1[j] = gp[rw * 16 + 8 + c];
        }

        // pass 0 matvec: my row = lane, cols 0..31 (weights via s_load)
        float acc0 = pre_b[0], acc1 = pre_b[1], acc2 = pre_b[2], acc3 = pre_b[3];
#pragma unroll
        for (int i = 0; i < 8; ++i) {
            float4 x  = wt[lane * 8 + (i ^ (lane & 7))];
            float4 w0 = pw4[0 * 16 + i];
            float4 w1 = pw4[1 * 16 + i];
            float4 w2 = pw4[2 * 16 + i];
            float4 w3 = pw4[3 * 16 + i];
            acc0 = fmaf(x.x, w0.x, acc0); acc0 = fmaf(x.y, w0.y, acc0);
            acc0 = fmaf(x.z, w0.z, acc0); acc0 = fmaf(x.w, w0.w, acc0);
            acc1 = fmaf(x.x, w1.x, acc1); acc1 = fmaf(x.y, w1.y, acc1);
            acc1 = fmaf(x.z, w1.z, acc1); acc1 = fmaf(x.w, w1.w, acc1);
            acc2 = fmaf(x.x, w2.x, acc2); acc2 = fmaf(x.y, w2.y, acc2);
            acc2 = fmaf(x.z, w2.z, acc2); acc2 = fmaf(x.w, w2.w, acc2);
            acc3 = fmaf(x.x, w3.x, acc3); acc3 = fmaf(x.y, w3.y, acc3);
            acc3 = fmaf(x.z, w3.z, acc3); acc3 = fmaf(x.w, w3.w, acc3);
        }

        // write + read pass 1 (same slots; in-order DS pipe makes WAR safe)
#pragma unroll
        for (int j = 0; j < 8; ++j) {
            int idx = j * 64 + lane;
            int rw = idx >> 3, c = idx & 7;
            wt[rw * 8 + (c ^ (rw & 7))] = x1[j];
        }
#pragma unroll
        for (int i = 0; i < 8; ++i) {
            float4 x  = wt[lane * 8 + (i ^ (lane & 7))];
            float4 w0 = pw4[0 * 16 + 8 + i];
            float4 w1 = pw4[1 * 16 + 8 + i];
            float4 w2 = pw4[2 * 16 + 8 + i];
            float4 w3 = pw4[3 * 16 + 8 + i];
            acc0 = fmaf(x.x, w0.x, acc0); acc0 = fmaf(x.y, w0.y, acc0);
            acc0 = fmaf(x.z, w0.z, acc0); acc0 = fmaf(x.w, w0.w, acc0);
            acc1 = fmaf(x.x, w1.x, acc1); acc1 = fmaf(x.y, w1.y, acc1);
            acc1 = fmaf(x.z, w1.z, acc1); acc1 = fmaf(x.w, w1.w, acc1);
            acc2 = fmaf(x.x, w2.x, acc2); acc2 = fmaf(x.y, w2.y, acc2);
            acc2 = fmaf(x.z, w2.z, acc2); acc2 = fmaf(x.w, w2.w, acc2);
            acc3 = fmaf(x.x, w3.x, acc3); acc3 = fmaf(x.y, w3.y, acc3);
            acc3 = fmaf(x.z, w3.z, acc3); acc3 = fmaf(x.w, w3.w, acc3);
        }

        // full angles: theta = tanh(pre)*pi/2; per-qubit basis (1, sin, cos)
        const float QH = 1.57079632679489662f;   // pi/2
        float th0 = fast_tanh(acc0) * QH;
        float th1 = fast_tanh(acc1) * QH;
        float th2 = fast_tanh(acc2) * QH;
        float th3 = fast_tanh(acc3) * QH;
        s0 = __sinf(th0); c0 = __cosf(th0);
        s1 = __sinf(th1); c1 = __cosf(th1);
        s2 = __sinf(th2); c2 = __cosf(th2);
        s3 = __sinf(th3); c3 = __cosf(th3);
    }

    // join: publishes wave-4's T4; matvec waves' vmem already consumed (no stall)
    __syncthreads();

    if (wave < 4) {
        // readout: out = sum_e T[e] * prod_w (1,sin,cos)[e_w]
        // 27 broadcast ds_read_b128 + ~93 FMA
        float r = 0.0f;
#pragma unroll
        for (int e0 = 0; e0 < 3; ++e0) {
            float a0 = 0.0f;
#pragma unroll
            for (int e1 = 0; e1 < 3; ++e1) {
                float a1 = 0.0f;
#pragma unroll
                for (int e2 = 0; e2 < 3; ++e2) {
                    float4 tb = T4[(e0 * 3 + e1) * 3 + e2];
                    float w = fmaf(c3, tb.z, fmaf(s3, tb.y, tb.x));
                    a1 = (e2 == 0) ? (a1 + w) : (e2 == 1) ? fmaf(s2, w, a1) : fmaf(c2, w, a1);
                }
                a0 = (e1 == 0) ? (a0 + a1) : (e1 == 1) ? fmaf(s1, a1, a0) : fmaf(c1, a1, a0);
            }
            r = (e0 == 0) ? (r + a0) : (e0 == 1) ? fmaf(s0, a0, r) : fmaf(c0, a0, r);
        }
        out[wrow0 + lane] = r;
    }
}

extern "C" void kernel_launch(void* const* d_in, const int* in_sizes, int n_in,
                              void* d_out, int out_size, void* d_ws, size_t ws_size,
                              hipStream_t stream) {
    const float* inp    = (const float*)d_in[0];
    const float* pre_w  = (const float*)d_in[1];
    const float* pre_b  = (const float*)d_in[2];
    const float* qp     = (const float*)d_in[3];
    const float* post_w = (const float*)d_in[4];
    const float* post_b = (const float*)d_in[5];
    float* out = (float*)d_out;

    int n = in_sizes[0] / ROWLEN;          // batch size (262144)
    int grid = n / 256;                    // 256 rows per block -> 1024 blocks
    dqnet_kernel<<<grid, TPB, 0, stream>>>(inp, pre_w, pre_b, qp, post_w, post_b, out);
}